// Round 3
// baseline (2795.038 us; speedup 1.0000x reference)
//
#include <hip/hip_runtime.h>
#include <hip/hip_bf16.h>
#include <math.h>

#define NU 50000
#define NFOOD 30000
#define NING 20000
#define NCAT 5000
#define NHAB 10000
#define NNODES 115000
#define NREL 8
#define NEDGE 1500000
#define H1COLS 1152   // 9*128 (8 relations + root)
#define H2COLS 18     // 8*2 + root(2)
#define SCAN_B 256

static inline size_t alignup(size_t x) { return (x + 255) & ~(size_t)255; }

__device__ inline float bf16_bits_to_f32(unsigned short u) {
  return __uint_as_float(((unsigned)u) << 16);
}
__device__ inline unsigned short f32_to_bf16_bits(float f) {
  unsigned u = __float_as_uint(f);
  unsigned r = u + 0x7fffu + ((u >> 16) & 1u);
  return (unsigned short)(r >> 16);
}

// ---------------- generic tiled fp32 GEMM: C[M,N] = A[M,K] @ B[K,N] (+bias) ---------
template <bool OUT_BF16>
__global__ __launch_bounds__(256) void gemm64(const float* __restrict__ A,
                                              const float* __restrict__ B,
                                              const float* __restrict__ bias,
                                              void* __restrict__ Cv,
                                              int M, int N, int K) {
  __shared__ float As[16][65];
  __shared__ float Bs[16][65];
  const int bm = blockIdx.y * 64;
  const int bn = blockIdx.x * 64;
  const int tid = threadIdx.x;
  const int tm = (tid >> 4) << 2;
  const int tn = (tid & 15) << 2;
  const int ar = tid >> 2;
  const int ac = (tid & 3) << 2;
  const int br = tid >> 4;
  const int bc = (tid & 15) << 2;
  float acc[4][4] = {};
  for (int k0 = 0; k0 < K; k0 += 16) {
    float4 a;
    if (bm + ar < M) a = *(const float4*)(A + (size_t)(bm + ar) * K + k0 + ac);
    else a = make_float4(0.f, 0.f, 0.f, 0.f);
    As[ac + 0][ar] = a.x;
    As[ac + 1][ar] = a.y;
    As[ac + 2][ar] = a.z;
    As[ac + 3][ar] = a.w;
    float4 b = *(const float4*)(B + (size_t)(k0 + br) * N + bn + bc);
    Bs[br][bc + 0] = b.x;
    Bs[br][bc + 1] = b.y;
    Bs[br][bc + 2] = b.z;
    Bs[br][bc + 3] = b.w;
    __syncthreads();
#pragma unroll
    for (int kk = 0; kk < 16; ++kk) {
      float av[4], bv[4];
#pragma unroll
      for (int i = 0; i < 4; ++i) av[i] = As[kk][tm + i];
#pragma unroll
      for (int j = 0; j < 4; ++j) bv[j] = Bs[kk][tn + j];
#pragma unroll
      for (int i = 0; i < 4; ++i)
#pragma unroll
        for (int j = 0; j < 4; ++j) acc[i][j] = fmaf(av[i], bv[j], acc[i][j]);
    }
    __syncthreads();
  }
#pragma unroll
  for (int i = 0; i < 4; ++i) {
    int row = bm + tm + i;
    if (row < M) {
#pragma unroll
      for (int j = 0; j < 4; ++j) {
        int col = bn + tn + j;
        float v = acc[i][j] + (bias ? bias[col] : 0.f);
        if (OUT_BF16)
          ((unsigned short*)Cv)[(size_t)row * N + col] = f32_to_bf16_bits(v);
        else
          ((float*)Cv)[(size_t)row * N + col] = v;
      }
    }
  }
}

// ---------------- weight repacks ---------------------------------------------------
__global__ void build_B1(const float* __restrict__ W1, const float* __restrict__ root1,
                         float* __restrict__ Bm) {
  int idx = blockIdx.x * blockDim.x + threadIdx.x;
  if (idx >= 128 * H1COLS) return;
  int d = idx / H1COLS, c = idx - d * H1COLS;
  int r = c >> 7, f = c & 127;
  Bm[idx] = (r < 8) ? W1[((size_t)r * 128 + d) * 128 + f] : root1[(size_t)d * 128 + f];
}

__global__ void build_B2(const float* __restrict__ W2, const float* __restrict__ root2,
                         float* __restrict__ Bm) {
  int idx = blockIdx.x * blockDim.x + threadIdx.x;
  if (idx >= 128 * H2COLS) return;
  int d = idx / H2COLS, c = idx - d * H2COLS;
  Bm[idx] = (c < 16) ? W2[((size_t)(c >> 1) * 128 + d) * 2 + (c & 1)]
                     : root2[(size_t)d * 2 + (c - 16)];
}

// ---------------- edge preprocessing ----------------------------------------------
// cnt[d*8+t] (f32, for mean weights) and cnt_dst[d] (int, for CSR)
__global__ void count_all(const int* __restrict__ ei, const int* __restrict__ et,
                          float* __restrict__ cnt, int* __restrict__ cnt_dst) {
  int e = blockIdx.x * blockDim.x + threadIdx.x;
  int stride = gridDim.x * blockDim.x;
  for (; e < NEDGE; e += stride) {
    unsigned d = (unsigned)ei[NEDGE + e]; if (d >= NNODES) d = 0;
    unsigned t = (unsigned)et[e];         if (t >= NREL)  t = 0;
    atomicAdd(cnt + (size_t)d * NREL + t, 1.0f);
    atomicAdd(cnt_dst + d, 1);
  }
}

// exclusive scan over cnt_dst -> row_ptr (2-level)
__global__ void scan_block(const int* __restrict__ in, int* __restrict__ out,
                           int* __restrict__ bsum, int n) {
  __shared__ int s[SCAN_B];
  int i = blockIdx.x * SCAN_B + threadIdx.x;
  int x = (i < n) ? in[i] : 0;
  s[threadIdx.x] = x;
  __syncthreads();
  for (int d = 1; d < SCAN_B; d <<= 1) {
    int v = (threadIdx.x >= d) ? s[threadIdx.x - d] : 0;
    __syncthreads();
    s[threadIdx.x] += v;
    __syncthreads();
  }
  if (i < n) out[i] = s[threadIdx.x] - x;          // exclusive within block
  if (threadIdx.x == SCAN_B - 1) bsum[blockIdx.x] = s[threadIdx.x];
}

__global__ void scan_top(int* __restrict__ bsum, int* __restrict__ bofs, int nb) {
  __shared__ int s[512];
  int x = (threadIdx.x < nb) ? bsum[threadIdx.x] : 0;
  s[threadIdx.x] = x;
  __syncthreads();
  for (int d = 1; d < 512; d <<= 1) {
    int v = (threadIdx.x >= d) ? s[threadIdx.x - d] : 0;
    __syncthreads();
    s[threadIdx.x] += v;
    __syncthreads();
  }
  if (threadIdx.x < nb) bofs[threadIdx.x] = s[threadIdx.x] - x;
}

__global__ void scan_apply(int* __restrict__ row_ptr, const int* __restrict__ bofs,
                           int* __restrict__ slot, int n) {
  int i = blockIdx.x * blockDim.x + threadIdx.x;
  if (i >= n) return;
  int v = row_ptr[i] + bofs[i / SCAN_B];
  row_ptr[i] = v;
  slot[i] = v;
}

// scatter packed (etype<<17)|src into dst-sorted order
__global__ void scatter_edges(const int* __restrict__ ei, const int* __restrict__ et,
                              int* __restrict__ slot, unsigned* __restrict__ packed) {
  int e = blockIdx.x * blockDim.x + threadIdx.x;
  int stride = gridDim.x * blockDim.x;
  for (; e < NEDGE; e += stride) {
    unsigned s = (unsigned)ei[e];         if (s >= NNODES) s = 0;
    unsigned d = (unsigned)ei[NEDGE + e]; if (d >= NNODES) d = 0;
    unsigned t = (unsigned)et[e];         if (t >= NREL)  t = 0;
    int pos = atomicAdd(slot + d, 1);
    packed[pos] = (t << 17) | s;
  }
}

// ---------------- fused layer-1 aggregation (wave per dst, no atomics) -------------
__global__ __launch_bounds__(256) void fused_agg1(
    const int* __restrict__ row_ptr, const unsigned* __restrict__ packed,
    const float* __restrict__ cnt, const unsigned* __restrict__ h1u,
    const float* __restrict__ b1, float* __restrict__ x1) {
  int lane = threadIdx.x & 63;
  int wid = (blockIdx.x * blockDim.x + threadIdx.x) >> 6;
  int nw = (gridDim.x * blockDim.x) >> 6;
  for (int d = wid; d < NNODES; d += nw) {
    int beg = row_ptr[d];
    int end = (d == NNODES - 1) ? NEDGE : row_ptr[d + 1];
    float a0 = 0.f, a1 = 0.f;
    for (int e = beg; e < end; ++e) {
      unsigned p = packed[e];
      unsigned s = p & 0x1FFFFu;
      unsigned t = p >> 17;
      float w = 1.0f / cnt[(size_t)d * NREL + t];
      unsigned u = h1u[(size_t)s * 576 + t * 64 + lane];
      a0 = fmaf(bf16_bits_to_f32((unsigned short)(u & 0xffffu)), w, a0);
      a1 = fmaf(bf16_bits_to_f32((unsigned short)(u >> 16)), w, a1);
    }
    unsigned u = h1u[(size_t)d * 576 + 512 + lane];   // root block
    a0 += bf16_bits_to_f32((unsigned short)(u & 0xffffu)) + b1[lane * 2];
    a1 += bf16_bits_to_f32((unsigned short)(u >> 16)) + b1[lane * 2 + 1];
    a0 = fmaxf(a0, 0.f);
    a1 = fmaxf(a1, 0.f);
    *(float2*)(x1 + (size_t)d * 128 + lane * 2) = make_float2(a0, a1);
  }
}

// h2[n, 0:18] = x1[n,:] @ B2   (wave per node)
__global__ __launch_bounds__(256) void l2_transform(const float* __restrict__ x1,
                                                    const float* __restrict__ B2,
                                                    float* __restrict__ h2) {
  __shared__ float sB[128 * H2COLS];
  for (int i = threadIdx.x; i < 128 * H2COLS; i += 256) sB[i] = B2[i];
  __syncthreads();
  int lane = threadIdx.x & 63;
  int wid = (blockIdx.x * blockDim.x + threadIdx.x) >> 6;
  int nw = (gridDim.x * blockDim.x) >> 6;
  for (int n = wid; n < NNODES; n += nw) {
    float a0 = x1[(size_t)n * 128 + lane];
    float a1 = x1[(size_t)n * 128 + 64 + lane];
    float p[H2COLS];
#pragma unroll
    for (int c = 0; c < H2COLS; ++c)
      p[c] = a0 * sB[lane * H2COLS + c] + a1 * sB[(lane + 64) * H2COLS + c];
#pragma unroll
    for (int c = 0; c < H2COLS; ++c)
#pragma unroll
      for (int off = 32; off; off >>= 1) p[c] += __shfl_xor(p[c], off, 64);
    if (lane == 0) {
#pragma unroll
      for (int c = 0; c < H2COLS; ++c) h2[(size_t)n * H2COLS + c] = p[c];
    }
  }
}

// ---------------- fused layer-2 aggregation + log_softmax (thread per dst) ---------
__global__ void fused_out(const int* __restrict__ row_ptr, const unsigned* __restrict__ packed,
                          const float* __restrict__ cnt, const float* __restrict__ h2,
                          const float* __restrict__ b2, float* __restrict__ out) {
  int d = blockIdx.x * blockDim.x + threadIdx.x;
  if (d >= NNODES) return;
  int beg = row_ptr[d];
  int end = (d == NNODES - 1) ? NEDGE : row_ptr[d + 1];
  float z0 = 0.f, z1 = 0.f;
  for (int e = beg; e < end; ++e) {
    unsigned p = packed[e];
    unsigned s = p & 0x1FFFFu;
    unsigned t = p >> 17;
    float w = 1.0f / cnt[(size_t)d * NREL + t];
    z0 = fmaf(h2[(size_t)s * H2COLS + t * 2], w, z0);
    z1 = fmaf(h2[(size_t)s * H2COLS + t * 2 + 1], w, z1);
  }
  z0 += h2[(size_t)d * H2COLS + 16] + b2[0];
  z1 += h2[(size_t)d * H2COLS + 17] + b2[1];
  float m = fmaxf(z0, z1);
  float l = m + logf(expf(z0 - m) + expf(z1 - m));
  out[(size_t)d * 2 + 0] = z0 - l;
  out[(size_t)d * 2 + 1] = z1 - l;
}

// ---------------- fallback (round-1) kernels ---------------------------------------
__global__ void edge_pass1_rel(const int* __restrict__ ei, const int* __restrict__ et,
                               const float* __restrict__ cnt,
                               const unsigned short* __restrict__ hr,
                               float* __restrict__ agg1, int r) {
  int gw = (blockIdx.x * blockDim.x + threadIdx.x) >> 6;
  int lane = threadIdx.x & 63;
  int nw = (gridDim.x * blockDim.x) >> 6;
  for (int e = gw; e < NEDGE; e += nw) {
    unsigned t = (unsigned)et[e]; if (t >= NREL) t = 0;
    if ((int)t != r) continue;
    unsigned s = (unsigned)ei[e];         if (s >= NNODES) s = 0;
    unsigned d = (unsigned)ei[NEDGE + e]; if (d >= NNODES) d = 0;
    float w = 1.0f / fmaxf(cnt[(size_t)d * NREL + t], 1.0f);
    unsigned u = ((const unsigned*)(hr + (size_t)s * 128))[lane];
    float lo = bf16_bits_to_f32((unsigned short)(u & 0xffffu));
    float hi = bf16_bits_to_f32((unsigned short)(u >> 16));
    float* dst = agg1 + (size_t)d * 128 + lane * 2;
    atomicAdd(dst, lo * w);
    atomicAdd(dst + 1, hi * w);
  }
}

__global__ void epi1(float* __restrict__ agg1, const float* __restrict__ b1) {
  int idx = blockIdx.x * blockDim.x + threadIdx.x;
  if (idx >= NNODES * 128) return;
  float v = agg1[idx] + b1[idx & 127];
  agg1[idx] = v > 0.f ? v : 0.f;
}

__global__ void edge_pass2(const int* __restrict__ ei, const int* __restrict__ et,
                           const float* __restrict__ cnt, const float* __restrict__ h2,
                           float* __restrict__ agg2) {
  int e = blockIdx.x * blockDim.x + threadIdx.x;
  int stride = gridDim.x * blockDim.x;
  for (; e < NEDGE; e += stride) {
    unsigned s = (unsigned)ei[e];         if (s >= NNODES) s = 0;
    unsigned d = (unsigned)ei[NEDGE + e]; if (d >= NNODES) d = 0;
    unsigned t = (unsigned)et[e];         if (t >= NREL) t = 0;
    float w = 1.0f / fmaxf(cnt[(size_t)d * NREL + t], 1.0f);
    atomicAdd(agg2 + (size_t)d * 2, h2[(size_t)s * H2COLS + t * 2] * w);
    atomicAdd(agg2 + (size_t)d * 2 + 1, h2[(size_t)s * H2COLS + t * 2 + 1] * w);
  }
}

__global__ void out_kernel(const float* __restrict__ agg2, const float* __restrict__ h2,
                           const float* __restrict__ b2, float* __restrict__ out) {
  int n = blockIdx.x * blockDim.x + threadIdx.x;
  if (n >= NNODES) return;
  float z0 = agg2[(size_t)n * 2 + 0] + h2[(size_t)n * H2COLS + 16] + b2[0];
  float z1 = agg2[(size_t)n * 2 + 1] + h2[(size_t)n * H2COLS + 17] + b2[1];
  float m = fmaxf(z0, z1);
  float l = m + logf(expf(z0 - m) + expf(z1 - m));
  out[(size_t)n * 2 + 0] = z0 - l;
  out[(size_t)n * 2 + 1] = z1 - l;
}

__global__ void fill_sentinel(float* __restrict__ out, int n, float v) {
  int i = blockIdx.x * blockDim.x + threadIdx.x;
  if (i < n) out[i] = v;
}

// -----------------------------------------------------------------------------------
extern "C" void kernel_launch(void* const* d_in, const int* in_sizes, int n_in,
                              void* d_out, int out_size, void* d_ws, size_t ws_size,
                              hipStream_t stream) {
  const float* x_user = (const float*)d_in[0];
  const float* x_food = (const float*)d_in[1];
  const float* x_ing  = (const float*)d_in[2];
  const float* x_cat  = (const float*)d_in[3];
  const float* x_hab  = (const float*)d_in[4];
  const float* Wu = (const float*)d_in[5];  const float* bu  = (const float*)d_in[6];
  const float* Wf = (const float*)d_in[7];  const float* bfo = (const float*)d_in[8];
  const float* Wi = (const float*)d_in[9];  const float* bi  = (const float*)d_in[10];
  const float* Wc = (const float*)d_in[11]; const float* bc  = (const float*)d_in[12];
  const float* Wh = (const float*)d_in[13]; const float* bh  = (const float*)d_in[14];
  const float* W1 = (const float*)d_in[15]; const float* root1 = (const float*)d_in[16];
  const float* b1 = (const float*)d_in[17];
  const float* W2 = (const float*)d_in[18]; const float* root2 = (const float*)d_in[19];
  const float* b2 = (const float*)d_in[20];
  const int* ei = (const int*)d_in[21];
  const int* et = (const int*)d_in[22];
  (void)in_sizes; (void)n_in; (void)out_size;

  dim3 blk(256);
  const int NB1 = (NNODES + SCAN_B - 1) / SCAN_B;   // 450

  // ---- fused-path workspace layout (~336 MB) ----
  {
    char* ws = (char*)d_ws;
    size_t off = 0;
    float* x_all = (float*)(ws + off);      off += alignup((size_t)NNODES * 128 * 4);
    unsigned short* h1 = (unsigned short*)(ws + off); off += alignup((size_t)NNODES * H1COLS * 2);
    float* Bm1 = (float*)(ws + off);        off += alignup((size_t)128 * H1COLS * 4);
    float* cnt = (float*)(ws + off);        off += alignup((size_t)NNODES * NREL * 4);
    int* cnt_dst = (int*)(ws + off);        off += alignup((size_t)NNODES * 4);
    int* row_ptr = (int*)(ws + off);        off += alignup((size_t)NNODES * 4);
    int* slot = (int*)(ws + off);           off += alignup((size_t)NNODES * 4);
    unsigned* packed = (unsigned*)(ws + off); off += alignup((size_t)NEDGE * 4);
    int* bsum = (int*)(ws + off);           off += alignup((size_t)512 * 4);
    int* bofs = (int*)(ws + off);           off += alignup((size_t)512 * 4);
    float* Bm2 = (float*)(ws + off);        off += alignup((size_t)128 * H2COLS * 4);
    size_t need_fused = off;
    float* x1 = x_all;        // x_all dead after h1 GEMM
    float* h2 = (float*)h1;   // h1 dead after fused_agg1

    if (ws_size >= need_fused) {
      hipMemsetAsync(cnt, 0, (size_t)NNODES * NREL * 4, stream);
      hipMemsetAsync(cnt_dst, 0, (size_t)NNODES * 4, stream);

      // projections
      { dim3 g(2, (NU + 63) / 64);
        gemm64<false><<<g, blk, 0, stream>>>(x_user, Wu, bu, (void*)(x_all), NU, 128, 256); }
      { dim3 g(2, (NFOOD + 63) / 64);
        gemm64<false><<<g, blk, 0, stream>>>(x_food, Wf, bfo, (void*)(x_all + (size_t)NU * 128), NFOOD, 128, 512); }
      { dim3 g(2, (NING + 63) / 64);
        gemm64<false><<<g, blk, 0, stream>>>(x_ing, Wi, bi, (void*)(x_all + (size_t)(NU + NFOOD) * 128), NING, 128, 128); }
      { dim3 g(2, (NCAT + 63) / 64);
        gemm64<false><<<g, blk, 0, stream>>>(x_cat, Wc, bc, (void*)(x_all + (size_t)(NU + NFOOD + NING) * 128), NCAT, 128, 64); }
      { dim3 g(2, (NHAB + 63) / 64);
        gemm64<false><<<g, blk, 0, stream>>>(x_hab, Wh, bh, (void*)(x_all + (size_t)(NU + NFOOD + NING + NCAT) * 128), NHAB, 128, 64); }

      // edge preprocessing: counts + CSR
      count_all<<<2048, blk, 0, stream>>>(ei, et, cnt, cnt_dst);
      scan_block<<<NB1, SCAN_B, 0, stream>>>(cnt_dst, row_ptr, bsum, NNODES);
      scan_top<<<1, 512, 0, stream>>>(bsum, bofs, NB1);
      scan_apply<<<NB1, SCAN_B, 0, stream>>>(row_ptr, bofs, slot, NNODES);
      scatter_edges<<<2048, blk, 0, stream>>>(ei, et, slot, packed);

      // h1 = x_all @ [W1|root1]  (bf16, one dispatch)
      build_B1<<<(128 * H1COLS + 255) / 256, blk, 0, stream>>>(W1, root1, Bm1);
      { dim3 g(H1COLS / 64, (NNODES + 63) / 64);
        gemm64<true><<<g, blk, 0, stream>>>(x_all, Bm1, nullptr, (void*)h1, NNODES, H1COLS, 128); }

      // layer-1 aggregation (gather, no atomics) -> x1
      fused_agg1<<<2048, blk, 0, stream>>>(row_ptr, packed, cnt, (const unsigned*)h1, b1, x1);

      // layer 2
      build_B2<<<(128 * H2COLS + 255) / 256, blk, 0, stream>>>(W2, root2, Bm2);
      l2_transform<<<2048, blk, 0, stream>>>(x1, Bm2, h2);
      fused_out<<<(NNODES + 255) / 256, blk, 0, stream>>>(row_ptr, packed, cnt, h2, b2, (float*)d_out);
      return;
    }
  }

  // ---- fallback: round-1 per-relation path (~152 MB) ----
  {
    char* ws = (char*)d_ws;
    size_t off = 0;
    float* x_all = (float*)(ws + off);  off += alignup((size_t)NNODES * 128 * 4);
    float* agg1  = (float*)(ws + off);  off += alignup((size_t)NNODES * 128 * 4);
    unsigned short* hr = (unsigned short*)(ws + off);
    off += alignup((size_t)NNODES * 128 * 2);
    float* cnt  = (float*)(ws + off);   off += alignup((size_t)NNODES * NREL * 4);
    float* Bm2  = (float*)(ws + off);   off += alignup((size_t)128 * H2COLS * 4);
    float* agg2 = (float*)(ws + off);   off += alignup((size_t)NNODES * 2 * 4);
    size_t needed = off;
    float* x1 = agg1;
    float* h2 = (float*)hr;

    if (ws_size < needed) {
      fill_sentinel<<<(out_size + 255) / 256, blk, 0, stream>>>((float*)d_out, out_size, -777.0f);
      return;
    }

    hipMemsetAsync(cnt, 0, (size_t)NNODES * NREL * 4, stream);
    hipMemsetAsync(agg2, 0, (size_t)NNODES * 2 * 4, stream);

    { dim3 g(2, (NU + 63) / 64);
      gemm64<false><<<g, blk, 0, stream>>>(x_user, Wu, bu, (void*)(x_all), NU, 128, 256); }
    { dim3 g(2, (NFOOD + 63) / 64);
      gemm64<false><<<g, blk, 0, stream>>>(x_food, Wf, bfo, (void*)(x_all + (size_t)NU * 128), NFOOD, 128, 512); }
    { dim3 g(2, (NING + 63) / 64);
      gemm64<false><<<g, blk, 0, stream>>>(x_ing, Wi, bi, (void*)(x_all + (size_t)(NU + NFOOD) * 128), NING, 128, 128); }
    { dim3 g(2, (NCAT + 63) / 64);
      gemm64<false><<<g, blk, 0, stream>>>(x_cat, Wc, bc, (void*)(x_all + (size_t)(NU + NFOOD + NING) * 128), NCAT, 128, 64); }
    { dim3 g(2, (NHAB + 63) / 64);
      gemm64<false><<<g, blk, 0, stream>>>(x_hab, Wh, bh, (void*)(x_all + (size_t)(NU + NFOOD + NING + NCAT) * 128), NHAB, 128, 64); }

    count_all<<<2048, blk, 0, stream>>>(ei, et, cnt, (int*)agg2);  // reuse agg2 as dummy? no:
    // NOTE: fallback needs plain count; agg2 misuse would corrupt. Use dedicated kernel-free fix:
    // re-zero agg2 after counting (cnt_dst values not needed in fallback).
    hipMemsetAsync(agg2, 0, (size_t)NNODES * 2 * 4, stream);

    { dim3 g(2, (NNODES + 63) / 64);
      gemm64<false><<<g, blk, 0, stream>>>(x_all, root1, nullptr, (void*)agg1, NNODES, 128, 128); }

    for (int r = 0; r < NREL; ++r) {
      dim3 g(2, (NNODES + 63) / 64);
      gemm64<true><<<g, blk, 0, stream>>>(x_all, W1 + (size_t)r * 128 * 128, nullptr,
                                          (void*)hr, NNODES, 128, 128);
      edge_pass1_rel<<<4096, blk, 0, stream>>>(ei, et, cnt, hr, agg1, r);
    }

    epi1<<<(NNODES * 128 + 255) / 256, blk, 0, stream>>>(agg1, b1);
    build_B2<<<(128 * H2COLS + 255) / 256, blk, 0, stream>>>(W2, root2, Bm2);
    l2_transform<<<2048, blk, 0, stream>>>(x1, Bm2, h2);
    edge_pass2<<<2048, blk, 0, stream>>>(ei, et, cnt, h2, agg2);
    out_kernel<<<(NNODES + 255) / 256, blk, 0, stream>>>(agg2, h2, b2, (float*)d_out);
  }
}

// Round 4
// 942.132 us; speedup vs baseline: 2.9667x; 2.9667x over previous
//
#include <hip/hip_runtime.h>
#include <hip/hip_bf16.h>
#include <math.h>

#define NU 50000
#define NFOOD 30000
#define NING 20000
#define NCAT 5000
#define NHAB 10000
#define NNODES 115000
#define NREL 8
#define NEDGE 1500000
#define H2COLS 18     // 8*2 + root(2)
#define SCAN_B 256

typedef __attribute__((ext_vector_type(8))) short short8;
typedef __attribute__((ext_vector_type(4))) float f32x4;

static inline size_t alignup(size_t x) { return (x + 255) & ~(size_t)255; }

__device__ inline float bf16_bits_to_f32(unsigned short u) {
  return __uint_as_float(((unsigned)u) << 16);
}
__device__ inline unsigned short f32_to_bf16_bits(float f) {
  unsigned u = __float_as_uint(f);
  unsigned r = u + 0x7fffu + ((u >> 16) & 1u);
  return (unsigned short)(r >> 16);
}

// ================= MFMA bf16 GEMM =================================================
// C[M,N] = A[M,K] @ B_T[N,K] (+bias).  A row-major (f32 or bf16); B stored TRANSPOSED
// [N][K] bf16.  Tile 128x128, BK=64, 256 threads = 4 waves, wave w owns rows w*32..+32.
// LDS tiles stored as [row][64 bf16] with 16B-unit XOR swizzle: byte ^= (row&7)<<4.
template <bool A_F32, bool OUT_BF16>
__global__ __launch_bounds__(256) void mfma_gemm(
    const void* __restrict__ Ain, const unsigned short* __restrict__ Bt,
    const float* __restrict__ bias, void* __restrict__ Cv,
    int M, int N, int K) {
  __shared__ char As[128 * 128];
  __shared__ char Bs[128 * 128];
  const int tid = threadIdx.x;
  const int lane = tid & 63;
  const int wv = tid >> 6;
  const int bm = blockIdx.y * 128;
  const int bn = blockIdx.x * 128;
  f32x4 acc[2][8] = {};

  for (int k0 = 0; k0 < K; k0 += 64) {
    // ---- stage A tile (128 rows x 64 bf16) ----
    if (A_F32) {
      const float* A = (const float*)Ain;
#pragma unroll
      for (int it = 0; it < 4; ++it) {
        int u = it * 256 + tid;
        int m = u >> 3, c = u & 7;
        int mg = bm + m; if (mg >= M) mg = M - 1;
        const float4* src = (const float4*)(A + (size_t)mg * K + k0 + c * 8);
        float4 lo4 = src[0], hi4 = src[1];
        unsigned q0 = f32_to_bf16_bits(lo4.x) | ((unsigned)f32_to_bf16_bits(lo4.y) << 16);
        unsigned q1 = f32_to_bf16_bits(lo4.z) | ((unsigned)f32_to_bf16_bits(lo4.w) << 16);
        unsigned q2 = f32_to_bf16_bits(hi4.x) | ((unsigned)f32_to_bf16_bits(hi4.y) << 16);
        unsigned q3 = f32_to_bf16_bits(hi4.z) | ((unsigned)f32_to_bf16_bits(hi4.w) << 16);
        int off = m * 128 + ((c * 16) ^ ((m & 7) << 4));
        *(int4*)(As + off) = make_int4(q0, q1, q2, q3);
      }
    } else {
      const unsigned short* A = (const unsigned short*)Ain;
#pragma unroll
      for (int it = 0; it < 4; ++it) {
        int u = it * 256 + tid;
        int m = u >> 3, c = u & 7;
        int mg = bm + m; if (mg >= M) mg = M - 1;
        int4 v = *(const int4*)((const char*)(A + (size_t)mg * K + k0) + c * 16);
        int off = m * 128 + ((c * 16) ^ ((m & 7) << 4));
        *(int4*)(As + off) = v;
      }
    }
    // ---- stage B_T tile (128 n-rows x 64 bf16); N is a multiple of 128 ----
#pragma unroll
    for (int it = 0; it < 4; ++it) {
      int u = it * 256 + tid;
      int n = u >> 3, c = u & 7;
      int4 v = *(const int4*)((const char*)(Bt + (size_t)(bn + n) * K + k0) + c * 16);
      int off = n * 128 + ((c * 16) ^ ((n & 7) << 4));
      *(int4*)(Bs + off) = v;
    }
    __syncthreads();
    // ---- MFMA: 2 k-steps of 32 ----
#pragma unroll
    for (int kk = 0; kk < 2; ++kk) {
      int kbyte = kk * 64 + ((lane >> 4) << 4);
      short8 af[2];
#pragma unroll
      for (int mi = 0; mi < 2; ++mi) {
        int m = wv * 32 + mi * 16 + (lane & 15);
        af[mi] = *(const short8*)(As + m * 128 + (kbyte ^ ((m & 7) << 4)));
      }
#pragma unroll
      for (int ni = 0; ni < 8; ++ni) {
        int n = ni * 16 + (lane & 15);
        short8 bf = *(const short8*)(Bs + n * 128 + (kbyte ^ ((n & 7) << 4)));
#pragma unroll
        for (int mi = 0; mi < 2; ++mi)
          acc[mi][ni] = __builtin_amdgcn_mfma_f32_16x16x32_bf16(af[mi], bf, acc[mi][ni], 0, 0, 0);
      }
    }
    __syncthreads();
  }
  // ---- epilogue: D row=(lane>>4)*4+r, col=lane&15 within each 16x16 fragment ----
#pragma unroll
  for (int mi = 0; mi < 2; ++mi) {
#pragma unroll
    for (int r = 0; r < 4; ++r) {
      int row = bm + wv * 32 + mi * 16 + ((lane >> 4) << 2) + r;
      if (row < M) {
#pragma unroll
        for (int ni = 0; ni < 8; ++ni) {
          int col = bn + ni * 16 + (lane & 15);
          float v = acc[mi][ni][r] + (bias ? bias[col] : 0.f);
          if (OUT_BF16)
            ((unsigned short*)Cv)[(size_t)row * N + col] = f32_to_bf16_bits(v);
          else
            ((float*)Cv)[(size_t)row * N + col] = v;
        }
      }
    }
  }
}

// ================= weight repacks (f32 -> transposed bf16) =========================
// W [K,N] f32 -> Wt [N,K] bf16
__global__ void build_Bt(const float* __restrict__ W, unsigned short* __restrict__ Wt,
                         int K, int N) {
  int idx = blockIdx.x * blockDim.x + threadIdx.x;
  if (idx >= N * K) return;
  int n = idx / K, k = idx - n * K;
  Wt[idx] = f32_to_bf16_bits(W[(size_t)k * N + n]);
}

// W1 [8,128,128] -> B1T [1152][128] bf16, row n = r*128+f holds W1[r][:,f]
__global__ void build_B1T(const float* __restrict__ W1, unsigned short* __restrict__ Bt) {
  int idx = blockIdx.x * blockDim.x + threadIdx.x;
  if (idx >= 1024 * 128) return;
  int n = idx >> 7, k = idx & 127;
  int r = n >> 7, f = n & 127;
  Bt[idx] = f32_to_bf16_bits(W1[((size_t)r * 128 + k) * 128 + f]);
}

__global__ void build_B2(const float* __restrict__ W2, const float* __restrict__ root2,
                         float* __restrict__ Bm) {
  int idx = blockIdx.x * blockDim.x + threadIdx.x;
  if (idx >= 128 * H2COLS) return;
  int d = idx / H2COLS, c = idx - d * H2COLS;
  Bm[idx] = (c < 16) ? W2[((size_t)(c >> 1) * 128 + d) * 2 + (c & 1)]
                     : root2[(size_t)d * 2 + (c - 16)];
}

// ================= edge preprocessing =============================================
__global__ void count_all(const int* __restrict__ ei, const int* __restrict__ et,
                          float* __restrict__ cnt, int* __restrict__ cnt_dst) {
  int e = blockIdx.x * blockDim.x + threadIdx.x;
  int stride = gridDim.x * blockDim.x;
  for (; e < NEDGE; e += stride) {
    unsigned d = (unsigned)ei[NEDGE + e]; if (d >= NNODES) d = 0;
    unsigned t = (unsigned)et[e];         if (t >= NREL)  t = 0;
    atomicAdd(cnt + (size_t)d * NREL + t, 1.0f);
    atomicAdd(cnt_dst + d, 1);
  }
}

__global__ void scan_block(const int* __restrict__ in, int* __restrict__ out,
                           int* __restrict__ bsum, int n) {
  __shared__ int s[SCAN_B];
  int i = blockIdx.x * SCAN_B + threadIdx.x;
  int x = (i < n) ? in[i] : 0;
  s[threadIdx.x] = x;
  __syncthreads();
  for (int d = 1; d < SCAN_B; d <<= 1) {
    int v = (threadIdx.x >= d) ? s[threadIdx.x - d] : 0;
    __syncthreads();
    s[threadIdx.x] += v;
    __syncthreads();
  }
  if (i < n) out[i] = s[threadIdx.x] - x;
  if (threadIdx.x == SCAN_B - 1) bsum[blockIdx.x] = s[threadIdx.x];
}

__global__ void scan_top(int* __restrict__ bsum, int* __restrict__ bofs, int nb) {
  __shared__ int s[512];
  int x = (threadIdx.x < nb) ? bsum[threadIdx.x] : 0;
  s[threadIdx.x] = x;
  __syncthreads();
  for (int d = 1; d < 512; d <<= 1) {
    int v = (threadIdx.x >= d) ? s[threadIdx.x - d] : 0;
    __syncthreads();
    s[threadIdx.x] += v;
    __syncthreads();
  }
  if (threadIdx.x < nb) bofs[threadIdx.x] = s[threadIdx.x] - x;
}

__global__ void scan_apply(int* __restrict__ row_ptr, const int* __restrict__ bofs,
                           int* __restrict__ slot, int n) {
  int i = blockIdx.x * blockDim.x + threadIdx.x;
  if (i >= n) return;
  int v = row_ptr[i] + bofs[i / SCAN_B];
  row_ptr[i] = v;
  slot[i] = v;
}

__global__ void scatter_edges(const int* __restrict__ ei, const int* __restrict__ et,
                              int* __restrict__ slot, unsigned* __restrict__ packed) {
  int e = blockIdx.x * blockDim.x + threadIdx.x;
  int stride = gridDim.x * blockDim.x;
  for (; e < NEDGE; e += stride) {
    unsigned s = (unsigned)ei[e];         if (s >= NNODES) s = 0;
    unsigned d = (unsigned)ei[NEDGE + e]; if (d >= NNODES) d = 0;
    unsigned t = (unsigned)et[e];         if (t >= NREL)  t = 0;
    int pos = atomicAdd(slot + d, 1);
    packed[pos] = (t << 17) | s;
  }
}

// ================= layer-1 gather (wave per dst, relation block [rb0, rb0+nrb)) ====
__global__ __launch_bounds__(256) void gather_agg1(
    const int* __restrict__ row_ptr, const unsigned* __restrict__ packed,
    const float* __restrict__ cnt, const unsigned short* __restrict__ hblk,
    float* __restrict__ agg1, int rb0, int nrb) {
  int lane = threadIdx.x & 63;
  int wid = (blockIdx.x * blockDim.x + threadIdx.x) >> 6;
  int nw = (gridDim.x * blockDim.x) >> 6;
  int hstride = nrb * 128;
  for (int d = wid; d < NNODES; d += nw) {
    int beg = row_ptr[d];
    int end = (d == NNODES - 1) ? NEDGE : row_ptr[d + 1];
    float a0 = 0.f, a1 = 0.f;
    bool touched = false;
    for (int e = beg; e < end; ++e) {
      unsigned p = packed[e];
      unsigned t = p >> 17;
      unsigned tt = t - (unsigned)rb0;
      if (tt >= (unsigned)nrb) continue;
      unsigned s = p & 0x1FFFFu;
      float w = 1.0f / cnt[(size_t)d * NREL + t];
      unsigned u = ((const unsigned*)(hblk + (size_t)s * hstride + tt * 128))[lane];
      a0 = fmaf(bf16_bits_to_f32((unsigned short)(u & 0xffffu)), w, a0);
      a1 = fmaf(bf16_bits_to_f32((unsigned short)(u >> 16)), w, a1);
      touched = true;
    }
    if (touched) {
      float2* p2 = (float2*)(agg1 + (size_t)d * 128 + lane * 2);
      float2 old = *p2;
      *p2 = make_float2(old.x + a0, old.y + a1);
    }
  }
}

// x1 = relu(agg1) in place (root @ b1 already included via root GEMM bias)
__global__ void epi1(float* __restrict__ agg1) {
  int idx = blockIdx.x * blockDim.x + threadIdx.x;
  if (idx >= NNODES * 128) return;
  float v = agg1[idx];
  agg1[idx] = v > 0.f ? v : 0.f;
}

// h2[n, 0:18] = x1[n,:] @ B2   (wave per node)
__global__ __launch_bounds__(256) void l2_transform(const float* __restrict__ x1,
                                                    const float* __restrict__ B2,
                                                    float* __restrict__ h2) {
  __shared__ float sB[128 * H2COLS];
  for (int i = threadIdx.x; i < 128 * H2COLS; i += 256) sB[i] = B2[i];
  __syncthreads();
  int lane = threadIdx.x & 63;
  int wid = (blockIdx.x * blockDim.x + threadIdx.x) >> 6;
  int nw = (gridDim.x * blockDim.x) >> 6;
  for (int n = wid; n < NNODES; n += nw) {
    float a0 = x1[(size_t)n * 128 + lane];
    float a1 = x1[(size_t)n * 128 + 64 + lane];
    float p[H2COLS];
#pragma unroll
    for (int c = 0; c < H2COLS; ++c)
      p[c] = a0 * sB[lane * H2COLS + c] + a1 * sB[(lane + 64) * H2COLS + c];
#pragma unroll
    for (int c = 0; c < H2COLS; ++c)
#pragma unroll
      for (int off = 32; off; off >>= 1) p[c] += __shfl_xor(p[c], off, 64);
    if (lane == 0) {
#pragma unroll
      for (int c = 0; c < H2COLS; ++c) h2[(size_t)n * H2COLS + c] = p[c];
    }
  }
}

// layer-2 aggregation + log_softmax (thread per dst, CSR)
__global__ void fused_out(const int* __restrict__ row_ptr, const unsigned* __restrict__ packed,
                          const float* __restrict__ cnt, const float* __restrict__ h2,
                          const float* __restrict__ b2, float* __restrict__ out) {
  int d = blockIdx.x * blockDim.x + threadIdx.x;
  if (d >= NNODES) return;
  int beg = row_ptr[d];
  int end = (d == NNODES - 1) ? NEDGE : row_ptr[d + 1];
  float z0 = 0.f, z1 = 0.f;
  for (int e = beg; e < end; ++e) {
    unsigned p = packed[e];
    unsigned s = p & 0x1FFFFu;
    unsigned t = p >> 17;
    float w = 1.0f / cnt[(size_t)d * NREL + t];
    z0 = fmaf(h2[(size_t)s * H2COLS + t * 2], w, z0);
    z1 = fmaf(h2[(size_t)s * H2COLS + t * 2 + 1], w, z1);
  }
  z0 += h2[(size_t)d * H2COLS + 16] + b2[0];
  z1 += h2[(size_t)d * H2COLS + 17] + b2[1];
  float m = fmaxf(z0, z1);
  float l = m + logf(expf(z0 - m) + expf(z1 - m));
  out[(size_t)d * 2 + 0] = z0 - l;
  out[(size_t)d * 2 + 1] = z1 - l;
}

__global__ void fill_sentinel(float* __restrict__ out, int n, float v) {
  int i = blockIdx.x * blockDim.x + threadIdx.x;
  if (i < n) out[i] = v;
}

// ===================================================================================
extern "C" void kernel_launch(void* const* d_in, const int* in_sizes, int n_in,
                              void* d_out, int out_size, void* d_ws, size_t ws_size,
                              hipStream_t stream) {
  const float* x_user = (const float*)d_in[0];
  const float* x_food = (const float*)d_in[1];
  const float* x_ing  = (const float*)d_in[2];
  const float* x_cat  = (const float*)d_in[3];
  const float* x_hab  = (const float*)d_in[4];
  const float* Wu = (const float*)d_in[5];  const float* bu  = (const float*)d_in[6];
  const float* Wf = (const float*)d_in[7];  const float* bfo = (const float*)d_in[8];
  const float* Wi = (const float*)d_in[9];  const float* bi  = (const float*)d_in[10];
  const float* Wc = (const float*)d_in[11]; const float* bc  = (const float*)d_in[12];
  const float* Wh = (const float*)d_in[13]; const float* bh  = (const float*)d_in[14];
  const float* W1 = (const float*)d_in[15]; const float* root1 = (const float*)d_in[16];
  const float* b1 = (const float*)d_in[17];
  const float* W2 = (const float*)d_in[18]; const float* root2 = (const float*)d_in[19];
  const float* b2 = (const float*)d_in[20];
  const int* ei = (const int*)d_in[21];
  const int* et = (const int*)d_in[22];
  (void)in_sizes; (void)n_in;

  dim3 blk(256);
  const int NB1 = (NNODES + SCAN_B - 1) / SCAN_B;   // 450

  // ---- workspace layout: fixed base + hblk tail (RB chosen to fit) ----
  char* ws = (char*)d_ws;
  size_t off = 0;
  unsigned short* x_all = (unsigned short*)(ws + off); off += alignup((size_t)NNODES * 128 * 2);
  float* agg1 = (float*)(ws + off);      off += alignup((size_t)NNODES * 128 * 4);
  float* cnt = (float*)(ws + off);       off += alignup((size_t)NNODES * NREL * 4);
  int* cnt_dst = (int*)(ws + off);       off += alignup((size_t)NNODES * 4);
  int* row_ptr = (int*)(ws + off);       off += alignup((size_t)NNODES * 4);
  int* slot = (int*)(ws + off);          off += alignup((size_t)NNODES * 4);
  unsigned* packed = (unsigned*)(ws + off); off += alignup((size_t)NEDGE * 4);
  int* bsum = (int*)(ws + off);          off += alignup((size_t)512 * 4);
  int* bofs = (int*)(ws + off);          off += alignup((size_t)512 * 4);
  unsigned short* WuT = (unsigned short*)(ws + off); off += alignup((size_t)128 * 256 * 2);
  unsigned short* WfT = (unsigned short*)(ws + off); off += alignup((size_t)128 * 512 * 2);
  unsigned short* WiT = (unsigned short*)(ws + off); off += alignup((size_t)128 * 128 * 2);
  unsigned short* WcT = (unsigned short*)(ws + off); off += alignup((size_t)128 * 64 * 2);
  unsigned short* WhT = (unsigned short*)(ws + off); off += alignup((size_t)128 * 64 * 2);
  unsigned short* rootT = (unsigned short*)(ws + off); off += alignup((size_t)128 * 128 * 2);
  unsigned short* B1T = (unsigned short*)(ws + off); off += alignup((size_t)1024 * 128 * 2);
  float* Bm2 = (float*)(ws + off);       off += alignup((size_t)128 * H2COLS * 4);
  unsigned short* hblk = (unsigned short*)(ws + off);   // tail
  size_t base = off;

  int RB = 0;
  for (int cand = 8; cand >= 1; cand >>= 1)
    if (base + (size_t)NNODES * cand * 128 * 2 <= ws_size) { RB = cand; break; }
  if (RB == 0) {
    fill_sentinel<<<(out_size + 255) / 256, blk, 0, stream>>>((float*)d_out, out_size, -777.0f);
    return;
  }
  float* h2 = (float*)hblk;  // hblk dead after gathers; 8.3 MB <= RB*29.4 MB

  hipMemsetAsync(cnt, 0, (size_t)NNODES * NREL * 4, stream);
  hipMemsetAsync(cnt_dst, 0, (size_t)NNODES * 4, stream);

  // ---- weight repacks ----
  build_Bt<<<(128 * 256 + 255) / 256, blk, 0, stream>>>(Wu, WuT, 256, 128);
  build_Bt<<<(128 * 512 + 255) / 256, blk, 0, stream>>>(Wf, WfT, 512, 128);
  build_Bt<<<(128 * 128 + 255) / 256, blk, 0, stream>>>(Wi, WiT, 128, 128);
  build_Bt<<<(128 * 64 + 255) / 256, blk, 0, stream>>>(Wc, WcT, 64, 128);
  build_Bt<<<(128 * 64 + 255) / 256, blk, 0, stream>>>(Wh, WhT, 64, 128);
  build_Bt<<<(128 * 128 + 255) / 256, blk, 0, stream>>>(root1, rootT, 128, 128);
  build_B1T<<<(1024 * 128 + 255) / 256, blk, 0, stream>>>(W1, B1T);
  build_B2<<<(128 * H2COLS + 255) / 256, blk, 0, stream>>>(W2, root2, Bm2);

  // ---- projections -> x_all (bf16) ----
  { dim3 g(1, (NU + 127) / 128);
    mfma_gemm<true, true><<<g, blk, 0, stream>>>(x_user, WuT, bu, (void*)x_all, NU, 128, 256); }
  { dim3 g(1, (NFOOD + 127) / 128);
    mfma_gemm<true, true><<<g, blk, 0, stream>>>(x_food, WfT, bfo, (void*)(x_all + (size_t)NU * 128), NFOOD, 128, 512); }
  { dim3 g(1, (NING + 127) / 128);
    mfma_gemm<true, true><<<g, blk, 0, stream>>>(x_ing, WiT, bi, (void*)(x_all + (size_t)(NU + NFOOD) * 128), NING, 128, 128); }
  { dim3 g(1, (NCAT + 127) / 128);
    mfma_gemm<true, true><<<g, blk, 0, stream>>>(x_cat, WcT, bc, (void*)(x_all + (size_t)(NU + NFOOD + NING) * 128), NCAT, 128, 64); }
  { dim3 g(1, (NHAB + 127) / 128);
    mfma_gemm<true, true><<<g, blk, 0, stream>>>(x_hab, WhT, bh, (void*)(x_all + (size_t)(NU + NFOOD + NING + NCAT) * 128), NHAB, 128, 64); }

  // ---- CSR build ----
  count_all<<<2048, blk, 0, stream>>>(ei, et, cnt, cnt_dst);
  scan_block<<<NB1, SCAN_B, 0, stream>>>(cnt_dst, row_ptr, bsum, NNODES);
  scan_top<<<1, 512, 0, stream>>>(bsum, bofs, NB1);
  scan_apply<<<NB1, SCAN_B, 0, stream>>>(row_ptr, bofs, slot, NNODES);
  scatter_edges<<<2048, blk, 0, stream>>>(ei, et, slot, packed);

  // ---- agg1 = x_all @ root1 + b1 (f32) ----
  { dim3 g(1, (NNODES + 127) / 128);
    mfma_gemm<false, false><<<g, blk, 0, stream>>>(x_all, rootT, b1, (void*)agg1, NNODES, 128, 128); }

  // ---- layer-1: relation blocks of RB ----
  for (int rb0 = 0; rb0 < NREL; rb0 += RB) {
    dim3 g(RB, (NNODES + 127) / 128);
    mfma_gemm<false, true><<<g, blk, 0, stream>>>(x_all, B1T + (size_t)rb0 * 128 * 128,
                                                  nullptr, (void*)hblk, NNODES, RB * 128, 128);
    gather_agg1<<<2048, blk, 0, stream>>>(row_ptr, packed, cnt, hblk, agg1, rb0, RB);
  }

  epi1<<<(NNODES * 128 + 255) / 256, blk, 0, stream>>>(agg1);

  // ---- layer 2 ----
  l2_transform<<<2048, blk, 0, stream>>>(agg1, Bm2, h2);
  fused_out<<<(NNODES + 255) / 256, blk, 0, stream>>>(row_ptr, packed, cnt, h2, b2, (float*)d_out);
}

// Round 5
// 773.294 us; speedup vs baseline: 3.6145x; 1.2183x over previous
//
#include <hip/hip_runtime.h>
#include <hip/hip_bf16.h>
#include <math.h>

#define NU 50000
#define NFOOD 30000
#define NING 20000
#define NCAT 5000
#define NHAB 10000
#define NNODES 115000
#define NREL 8
#define NEDGE 1500000
#define SCAN_B 256

typedef __attribute__((ext_vector_type(8))) short short8;
typedef __attribute__((ext_vector_type(4))) float f32x4;

static inline size_t alignup(size_t x) { return (x + 255) & ~(size_t)255; }

__device__ inline float bf16_bits_to_f32(unsigned short u) {
  return __uint_as_float(((unsigned)u) << 16);
}
__device__ inline unsigned short f32_to_bf16_bits(float f) {
  unsigned u = __float_as_uint(f);
  unsigned r = u + 0x7fffu + ((u >> 16) & 1u);
  return (unsigned short)(r >> 16);
}

// ================= MFMA bf16 GEMM ==================================================
// C[M,N] = op(A)[M,K] @ B_T[N,K] (+bias) (+C if ACC).  A row-major, lda==K.
// Bt row-major [N][ldB] bf16.  Tile 128x128, BK=64, 256 thr = 4 waves.
// LDS [row][64 bf16], 16B-unit XOR swizzle byte ^= (row&7)<<4.
template <bool A_F32, bool OUT_BF16, bool ACC, bool RELU>
__global__ __launch_bounds__(256) void mfma_gemm(
    const void* __restrict__ Ain, const unsigned short* __restrict__ Bt, int ldB,
    const float* __restrict__ bias, void* __restrict__ Cv, int ldC, int Nstore,
    int M, int N, int K) {
  __shared__ char As[128 * 128];
  __shared__ char Bs[128 * 128];
  const int tid = threadIdx.x;
  const int lane = tid & 63;
  const int wv = tid >> 6;
  const int bm = blockIdx.y * 128;
  const int bn = blockIdx.x * 128;
  f32x4 acc[2][8] = {};

  for (int k0 = 0; k0 < K; k0 += 64) {
    if (A_F32) {
      const float* A = (const float*)Ain;
#pragma unroll
      for (int it = 0; it < 4; ++it) {
        int u = it * 256 + tid;
        int m = u >> 3, c = u & 7;
        int mg = bm + m; if (mg >= M) mg = M - 1;
        const float4* src = (const float4*)(A + (size_t)mg * K + k0 + c * 8);
        float4 lo4 = src[0], hi4 = src[1];
        if (RELU) {
          lo4.x = fmaxf(lo4.x, 0.f); lo4.y = fmaxf(lo4.y, 0.f);
          lo4.z = fmaxf(lo4.z, 0.f); lo4.w = fmaxf(lo4.w, 0.f);
          hi4.x = fmaxf(hi4.x, 0.f); hi4.y = fmaxf(hi4.y, 0.f);
          hi4.z = fmaxf(hi4.z, 0.f); hi4.w = fmaxf(hi4.w, 0.f);
        }
        unsigned q0 = f32_to_bf16_bits(lo4.x) | ((unsigned)f32_to_bf16_bits(lo4.y) << 16);
        unsigned q1 = f32_to_bf16_bits(lo4.z) | ((unsigned)f32_to_bf16_bits(lo4.w) << 16);
        unsigned q2 = f32_to_bf16_bits(hi4.x) | ((unsigned)f32_to_bf16_bits(hi4.y) << 16);
        unsigned q3 = f32_to_bf16_bits(hi4.z) | ((unsigned)f32_to_bf16_bits(hi4.w) << 16);
        int off = m * 128 + ((c * 16) ^ ((m & 7) << 4));
        *(int4*)(As + off) = make_int4(q0, q1, q2, q3);
      }
    } else {
      const unsigned short* A = (const unsigned short*)Ain;
#pragma unroll
      for (int it = 0; it < 4; ++it) {
        int u = it * 256 + tid;
        int m = u >> 3, c = u & 7;
        int mg = bm + m; if (mg >= M) mg = M - 1;
        int4 v = *(const int4*)((const char*)(A + (size_t)mg * K + k0) + c * 16);
        int off = m * 128 + ((c * 16) ^ ((m & 7) << 4));
        *(int4*)(As + off) = v;
      }
    }
#pragma unroll
    for (int it = 0; it < 4; ++it) {
      int u = it * 256 + tid;
      int n = u >> 3, c = u & 7;
      int4 v = *(const int4*)((const char*)(Bt + (size_t)(bn + n) * ldB + k0) + c * 16);
      int off = n * 128 + ((c * 16) ^ ((n & 7) << 4));
      *(int4*)(Bs + off) = v;
    }
    __syncthreads();
#pragma unroll
    for (int kk = 0; kk < 2; ++kk) {
      int kbyte = kk * 64 + ((lane >> 4) << 4);
      short8 af[2];
#pragma unroll
      for (int mi = 0; mi < 2; ++mi) {
        int m = wv * 32 + mi * 16 + (lane & 15);
        af[mi] = *(const short8*)(As + m * 128 + (kbyte ^ ((m & 7) << 4)));
      }
#pragma unroll
      for (int ni = 0; ni < 8; ++ni) {
        int n = ni * 16 + (lane & 15);
        short8 bf = *(const short8*)(Bs + n * 128 + (kbyte ^ ((n & 7) << 4)));
#pragma unroll
        for (int mi = 0; mi < 2; ++mi)
          acc[mi][ni] = __builtin_amdgcn_mfma_f32_16x16x32_bf16(af[mi], bf, acc[mi][ni], 0, 0, 0);
      }
    }
    __syncthreads();
  }
#pragma unroll
  for (int mi = 0; mi < 2; ++mi) {
#pragma unroll
    for (int r = 0; r < 4; ++r) {
      int row = bm + wv * 32 + mi * 16 + ((lane >> 4) << 2) + r;
      if (row < M) {
#pragma unroll
        for (int ni = 0; ni < 8; ++ni) {
          int col = bn + ni * 16 + (lane & 15);
          if (col < Nstore) {
            float v = acc[mi][ni][r] + (bias ? bias[col] : 0.f);
            if (ACC) v += ((const float*)Cv)[(size_t)row * ldC + col];
            if (OUT_BF16)
              ((unsigned short*)Cv)[(size_t)row * ldC + col] = f32_to_bf16_bits(v);
            else
              ((float*)Cv)[(size_t)row * ldC + col] = v;
          }
        }
      }
    }
  }
}

// ================= weight repacks ==================================================
// W [K,N] f32 -> Wt [N][K] bf16
__global__ void build_Bt(const float* __restrict__ W, unsigned short* __restrict__ Wt,
                         int K, int N) {
  int idx = blockIdx.x * blockDim.x + threadIdx.x;
  if (idx >= N * K) return;
  int n = idx / K, k = idx - n * K;
  Wt[idx] = f32_to_bf16_bits(W[(size_t)k * N + n]);
}

// W1 [8,128,128] -> W1T [128][1024] bf16: W1T[f][t*128+k] = W1[t][k][f]
__global__ void build_W1T(const float* __restrict__ W1, unsigned short* __restrict__ Wt) {
  int idx = blockIdx.x * blockDim.x + threadIdx.x;
  if (idx >= 128 * 1024) return;
  int f = idx >> 10, c = idx & 1023;
  int t = c >> 7, k = c & 127;
  Wt[idx] = f32_to_bf16_bits(W1[((size_t)t * 128 + k) * 128 + f]);
}

// B2pad [128][128] bf16: row n<16: W2[n>>1][k][n&1]; n in [16,18): root2[k][n-16]; else 0
__global__ void build_B2pad(const float* __restrict__ W2, const float* __restrict__ root2,
                            unsigned short* __restrict__ Bt) {
  int idx = blockIdx.x * blockDim.x + threadIdx.x;
  if (idx >= 128 * 128) return;
  int n = idx >> 7, k = idx & 127;
  float v = 0.f;
  if (n < 16) v = W2[((size_t)(n >> 1) * 128 + k) * 2 + (n & 1)];
  else if (n < 18) v = root2[(size_t)k * 2 + (n - 16)];
  Bt[idx] = f32_to_bf16_bits(v);
}

// ================= CSR build =======================================================
__global__ void count_dst(const int* __restrict__ ei, int* __restrict__ cnt_dst) {
  int e = blockIdx.x * blockDim.x + threadIdx.x;
  int stride = gridDim.x * blockDim.x;
  for (; e < NEDGE; e += stride) {
    unsigned d = (unsigned)ei[NEDGE + e]; if (d >= NNODES) d = 0;
    atomicAdd(cnt_dst + d, 1);
  }
}

__global__ void scan_block(const int* __restrict__ in, int* __restrict__ out,
                           int* __restrict__ bsum, int n) {
  __shared__ int s[SCAN_B];
  int i = blockIdx.x * SCAN_B + threadIdx.x;
  int x = (i < n) ? in[i] : 0;
  s[threadIdx.x] = x;
  __syncthreads();
  for (int d = 1; d < SCAN_B; d <<= 1) {
    int v = (threadIdx.x >= d) ? s[threadIdx.x - d] : 0;
    __syncthreads();
    s[threadIdx.x] += v;
    __syncthreads();
  }
  if (i < n) out[i] = s[threadIdx.x] - x;
  if (threadIdx.x == SCAN_B - 1) bsum[blockIdx.x] = s[threadIdx.x];
}

__global__ void scan_top(int* __restrict__ bsum, int* __restrict__ bofs, int nb) {
  __shared__ int s[512];
  int x = (threadIdx.x < nb) ? bsum[threadIdx.x] : 0;
  s[threadIdx.x] = x;
  __syncthreads();
  for (int d = 1; d < 512; d <<= 1) {
    int v = (threadIdx.x >= d) ? s[threadIdx.x - d] : 0;
    __syncthreads();
    s[threadIdx.x] += v;
    __syncthreads();
  }
  if (threadIdx.x < nb) bofs[threadIdx.x] = s[threadIdx.x] - x;
}

__global__ void scan_apply(int* __restrict__ row_ptr, const int* __restrict__ bofs,
                           int* __restrict__ slot, int n) {
  int i = blockIdx.x * blockDim.x + threadIdx.x;
  if (i >= n) return;
  int v = row_ptr[i] + bofs[i / SCAN_B];
  row_ptr[i] = v;
  slot[i] = v;
}

__global__ void scatter_edges(const int* __restrict__ ei, const int* __restrict__ et,
                              int* __restrict__ slot, unsigned* __restrict__ packed) {
  int e = blockIdx.x * blockDim.x + threadIdx.x;
  int stride = gridDim.x * blockDim.x;
  for (; e < NEDGE; e += stride) {
    unsigned s = (unsigned)ei[e];         if (s >= NNODES) s = 0;
    unsigned d = (unsigned)ei[NEDGE + e]; if (d >= NNODES) d = 0;
    unsigned t = (unsigned)et[e];         if (t >= NREL)  t = 0;
    int pos = atomicAdd(slot + d, 1);
    packed[pos] = (t << 17) | s;
  }
}

// ============ layer-1 gather-means in x-space (wave per dst) =======================
// M_blk[d][rr*128 + f] = mean over edges (s->d, rel rb0+rr) of x_all[s][f]  (bf16)
template <int NRB>
__global__ __launch_bounds__(256) void gather_means(
    const int* __restrict__ row_ptr, const unsigned* __restrict__ packed,
    const unsigned* __restrict__ xu, unsigned* __restrict__ Mb, int rb0) {
  int lane = threadIdx.x & 63;
  int wid = (blockIdx.x * blockDim.x + threadIdx.x) >> 6;
  int nw = (gridDim.x * blockDim.x) >> 6;
  for (int d = wid; d < NNODES; d += nw) {
    int beg = row_ptr[d];
    int end = (d == NNODES - 1) ? NEDGE : row_ptr[d + 1];
    float a0[NRB], a1[NRB];
    int c[NRB];
#pragma unroll
    for (int q = 0; q < NRB; ++q) { a0[q] = 0.f; a1[q] = 0.f; c[q] = 0; }
    for (int e = beg; e < end; ++e) {
      unsigned p = packed[e];
      int tt = (int)(p >> 17) - rb0;
      if ((unsigned)tt >= (unsigned)NRB) continue;
      unsigned u = xu[(size_t)(p & 0x1FFFFu) * 64 + lane];
      float lo = bf16_bits_to_f32((unsigned short)(u & 0xffffu));
      float hi = bf16_bits_to_f32((unsigned short)(u >> 16));
#pragma unroll
      for (int q = 0; q < NRB; ++q)
        if (tt == q) { a0[q] += lo; a1[q] += hi; c[q]++; }
    }
#pragma unroll
    for (int q = 0; q < NRB; ++q) {
      float w = 1.0f / (float)(c[q] > 0 ? c[q] : 1);
      unsigned out = f32_to_bf16_bits(a0[q] * w) |
                     ((unsigned)f32_to_bf16_bits(a1[q] * w) << 16);
      Mb[(size_t)d * (NRB * 64) + q * 64 + lane] = out;
    }
  }
}

// ============ layer-2 aggregation + log_softmax (4 lanes per dst) ==================
__global__ void fused_out(const int* __restrict__ row_ptr, const unsigned* __restrict__ packed,
                          const float* __restrict__ h2, const float* __restrict__ b2,
                          float* __restrict__ out) {
  int gt = blockIdx.x * blockDim.x + threadIdx.x;
  int d = gt >> 2;
  int l4 = gt & 3;
  if (d >= NNODES) return;
  int beg = row_ptr[d];
  int end = (d == NNODES - 1) ? NEDGE : row_ptr[d + 1];
  int cnts[8];
#pragma unroll
  for (int q = 0; q < 8; ++q) cnts[q] = 0;
  for (int e = beg; e < end; ++e) {
    unsigned t = packed[e] >> 17;
#pragma unroll
    for (int q = 0; q < 8; ++q) cnts[q] += (t == (unsigned)q);
  }
  float z0 = 0.f, z1 = 0.f;
  for (int e = beg + l4; e < end; e += 4) {
    unsigned p = packed[e];
    unsigned s = p & 0x1FFFFu;
    unsigned t = p >> 17;
    int ct = 1;
#pragma unroll
    for (int q = 0; q < 8; ++q) ct = (t == (unsigned)q) ? cnts[q] : ct;
    float w = 1.0f / (float)(ct > 0 ? ct : 1);
    z0 = fmaf(h2[(size_t)s * 18 + t * 2], w, z0);
    z1 = fmaf(h2[(size_t)s * 18 + t * 2 + 1], w, z1);
  }
  z0 += __shfl_xor(z0, 1, 4); z0 += __shfl_xor(z0, 2, 4);
  z1 += __shfl_xor(z1, 1, 4); z1 += __shfl_xor(z1, 2, 4);
  if (l4 == 0) {
    z0 += h2[(size_t)d * 18 + 16] + b2[0];
    z1 += h2[(size_t)d * 18 + 17] + b2[1];
    float m = fmaxf(z0, z1);
    float l = m + logf(expf(z0 - m) + expf(z1 - m));
    out[(size_t)d * 2 + 0] = z0 - l;
    out[(size_t)d * 2 + 1] = z1 - l;
  }
}

__global__ void fill_sentinel(float* __restrict__ out, int n, float v) {
  int i = blockIdx.x * blockDim.x + threadIdx.x;
  if (i < n) out[i] = v;
}

// ===================================================================================
extern "C" void kernel_launch(void* const* d_in, const int* in_sizes, int n_in,
                              void* d_out, int out_size, void* d_ws, size_t ws_size,
                              hipStream_t stream) {
  const float* x_user = (const float*)d_in[0];
  const float* x_food = (const float*)d_in[1];
  const float* x_ing  = (const float*)d_in[2];
  const float* x_cat  = (const float*)d_in[3];
  const float* x_hab  = (const float*)d_in[4];
  const float* Wu = (const float*)d_in[5];  const float* bu  = (const float*)d_in[6];
  const float* Wf = (const float*)d_in[7];  const float* bfo = (const float*)d_in[8];
  const float* Wi = (const float*)d_in[9];  const float* bi  = (const float*)d_in[10];
  const float* Wc = (const float*)d_in[11]; const float* bc  = (const float*)d_in[12];
  const float* Wh = (const float*)d_in[13]; const float* bh  = (const float*)d_in[14];
  const float* W1 = (const float*)d_in[15]; const float* root1 = (const float*)d_in[16];
  const float* b1 = (const float*)d_in[17];
  const float* W2 = (const float*)d_in[18]; const float* root2 = (const float*)d_in[19];
  const float* b2 = (const float*)d_in[20];
  const int* ei = (const int*)d_in[21];
  const int* et = (const int*)d_in[22];
  (void)in_sizes; (void)n_in;

  dim3 blk(256);
  const int NB1 = (NNODES + SCAN_B - 1) / SCAN_B;   // 450

  // ---- workspace layout: fixed base + M_blk tail ----
  char* ws = (char*)d_ws;
  size_t off = 0;
  unsigned short* x_all = (unsigned short*)(ws + off); off += alignup((size_t)NNODES * 128 * 2);
  float* agg1 = (float*)(ws + off);      off += alignup((size_t)NNODES * 128 * 4);
  int* cnt_dst = (int*)(ws + off);       off += alignup((size_t)NNODES * 4);
  int* row_ptr = (int*)(ws + off);       off += alignup((size_t)NNODES * 4);
  int* slot = (int*)(ws + off);          off += alignup((size_t)NNODES * 4);
  unsigned* packed = (unsigned*)(ws + off); off += alignup((size_t)NEDGE * 4);
  int* bsum = (int*)(ws + off);          off += alignup((size_t)512 * 4);
  int* bofs = (int*)(ws + off);          off += alignup((size_t)512 * 4);
  unsigned short* WuT = (unsigned short*)(ws + off); off += alignup((size_t)128 * 256 * 2);
  unsigned short* WfT = (unsigned short*)(ws + off); off += alignup((size_t)128 * 512 * 2);
  unsigned short* WiT = (unsigned short*)(ws + off); off += alignup((size_t)128 * 128 * 2);
  unsigned short* WcT = (unsigned short*)(ws + off); off += alignup((size_t)128 * 64 * 2);
  unsigned short* WhT = (unsigned short*)(ws + off); off += alignup((size_t)128 * 64 * 2);
  unsigned short* rootT = (unsigned short*)(ws + off); off += alignup((size_t)128 * 128 * 2);
  unsigned short* W1T = (unsigned short*)(ws + off); off += alignup((size_t)128 * 1024 * 2);
  unsigned short* B2pad = (unsigned short*)(ws + off); off += alignup((size_t)128 * 128 * 2);
  unsigned short* M_blk = (unsigned short*)(ws + off);   // tail
  size_t base = off;

  int RB = 0;
  for (int cand = 4; cand >= 1; cand >>= 1)
    if (base + (size_t)NNODES * cand * 128 * 2 <= ws_size) { RB = cand; break; }
  if (RB == 0) {
    fill_sentinel<<<(out_size + 255) / 256, blk, 0, stream>>>((float*)d_out, out_size, -777.0f);
    return;
  }
  float* h2 = (float*)M_blk;  // M_blk dead after last accum GEMM; 8.3 MB <= RB*29.4 MB

  hipMemsetAsync(cnt_dst, 0, (size_t)NNODES * 4, stream);

  // ---- weight repacks ----
  build_Bt<<<(128 * 256 + 255) / 256, blk, 0, stream>>>(Wu, WuT, 256, 128);
  build_Bt<<<(128 * 512 + 255) / 256, blk, 0, stream>>>(Wf, WfT, 512, 128);
  build_Bt<<<(128 * 128 + 255) / 256, blk, 0, stream>>>(Wi, WiT, 128, 128);
  build_Bt<<<(128 * 64 + 255) / 256, blk, 0, stream>>>(Wc, WcT, 64, 128);
  build_Bt<<<(128 * 64 + 255) / 256, blk, 0, stream>>>(Wh, WhT, 64, 128);
  build_Bt<<<(128 * 128 + 255) / 256, blk, 0, stream>>>(root1, rootT, 128, 128);
  build_W1T<<<(128 * 1024 + 255) / 256, blk, 0, stream>>>(W1, W1T);
  build_B2pad<<<(128 * 128 + 255) / 256, blk, 0, stream>>>(W2, root2, B2pad);

  // ---- projections -> x_all (bf16) ----
  { dim3 g(1, (NU + 127) / 128);
    mfma_gemm<true, true, false, false><<<g, blk, 0, stream>>>(x_user, WuT, 256, bu, (void*)x_all, 128, 128, NU, 128, 256); }
  { dim3 g(1, (NFOOD + 127) / 128);
    mfma_gemm<true, true, false, false><<<g, blk, 0, stream>>>(x_food, WfT, 512, bfo, (void*)(x_all + (size_t)NU * 128), 128, 128, NFOOD, 128, 512); }
  { dim3 g(1, (NING + 127) / 128);
    mfma_gemm<true, true, false, false><<<g, blk, 0, stream>>>(x_ing, WiT, 128, bi, (void*)(x_all + (size_t)(NU + NFOOD) * 128), 128, 128, NING, 128, 128); }
  { dim3 g(1, (NCAT + 127) / 128);
    mfma_gemm<true, true, false, false><<<g, blk, 0, stream>>>(x_cat, WcT, 64, bc, (void*)(x_all + (size_t)(NU + NFOOD + NING) * 128), 128, 128, NCAT, 128, 64); }
  { dim3 g(1, (NHAB + 127) / 128);
    mfma_gemm<true, true, false, false><<<g, blk, 0, stream>>>(x_hab, WhT, 64, bh, (void*)(x_all + (size_t)(NU + NFOOD + NING + NCAT) * 128), 128, 128, NHAB, 128, 64); }

  // ---- CSR build ----
  count_dst<<<2048, blk, 0, stream>>>(ei, cnt_dst);
  scan_block<<<NB1, SCAN_B, 0, stream>>>(cnt_dst, row_ptr, bsum, NNODES);
  scan_top<<<1, 512, 0, stream>>>(bsum, bofs, NB1);
  scan_apply<<<NB1, SCAN_B, 0, stream>>>(row_ptr, bofs, slot, NNODES);
  scatter_edges<<<2048, blk, 0, stream>>>(ei, et, slot, packed);

  // ---- agg1 = x_all @ root1 + b1 ----
  { dim3 g(1, (NNODES + 127) / 128);
    mfma_gemm<false, false, false, false><<<g, blk, 0, stream>>>(x_all, rootT, 128, b1, (void*)agg1, 128, 128, NNODES, 128, 128); }

  // ---- layer 1: per relation-block gather-means then accum GEMM ----
  for (int rb0 = 0; rb0 < NREL; rb0 += RB) {
    if (RB == 4)
      gather_means<4><<<2048, blk, 0, stream>>>(row_ptr, packed, (const unsigned*)x_all, (unsigned*)M_blk, rb0);
    else if (RB == 2)
      gather_means<2><<<2048, blk, 0, stream>>>(row_ptr, packed, (const unsigned*)x_all, (unsigned*)M_blk, rb0);
    else
      gather_means<1><<<2048, blk, 0, stream>>>(row_ptr, packed, (const unsigned*)x_all, (unsigned*)M_blk, rb0);
    dim3 g(1, (NNODES + 127) / 128);
    mfma_gemm<false, false, true, false><<<g, blk, 0, stream>>>(M_blk, W1T + (size_t)rb0 * 128, 1024, nullptr, (void*)agg1, 128, 128, NNODES, 128, RB * 128);
  }

  // ---- layer 2: h2 = relu(agg1) @ B2pad (store 18 cols) ----
  { dim3 g(1, (NNODES + 127) / 128);
    mfma_gemm<true, false, false, true><<<g, blk, 0, stream>>>(agg1, B2pad, 128, nullptr, (void*)h2, 18, 18, NNODES, 128, 128); }

  fused_out<<<(NNODES * 4 + 255) / 256, blk, 0, stream>>>(row_ptr, packed, h2, b2, (float*)d_out);
}